// Round 2
// baseline (562.635 us; speedup 1.0000x reference)
//
#include <hip/hip_runtime.h>
#include <math.h>

// Shapes
#define B_   128
#define D_   1024
#define H_   256
#define M_   100
#define K_   5
#define MD   102400   // M_*D_
#define EPS_ 1e-5f

// d_out layout (f32): probs[128*100*1024], scores[12800], syn[12800], logits[128*100*1024]
#define OFF_SCORES 13107200
#define OFF_SYN    13120000
#define OFF_LOGITS 13132800

// ---------------- reduction helpers ----------------
__device__ __forceinline__ float block_sum(float v, float* red, int t) {
  #pragma unroll
  for (int off = 1; off < 64; off <<= 1) v += __shfl_xor(v, off);
  if ((t & 63) == 0) red[t >> 6] = v;
  __syncthreads();
  float s = red[0] + red[1] + red[2] + red[3];
  __syncthreads();
  return s;
}

__device__ __forceinline__ float block_max(float v, float* red, int t) {
  #pragma unroll
  for (int off = 1; off < 64; off <<= 1) v = fmaxf(v, __shfl_xor(v, off));
  if ((t & 63) == 0) red[t >> 6] = v;
  __syncthreads();
  float s = fmaxf(fmaxf(red[0], red[1]), fmaxf(red[2], red[3]));
  __syncthreads();
  return s;
}

__device__ __forceinline__ void block_sum2(float& a, float& b, float* red, int t) {
  #pragma unroll
  for (int off = 1; off < 64; off <<= 1) { a += __shfl_xor(a, off); b += __shfl_xor(b, off); }
  if ((t & 63) == 0) { red[(t >> 6) * 2] = a; red[(t >> 6) * 2 + 1] = b; }
  __syncthreads();
  a = red[0] + red[2] + red[4] + red[6];
  b = red[1] + red[3] + red[5] + red[7];
  __syncthreads();
}

// ---------------- K1: generator layers 1+2 (per batch row) ----------------
__global__ __launch_bounds__(256) void gen_mlp_kernel(
    const float* __restrict__ x,
    const float* __restrict__ gW1, const float* __restrict__ gb1,
    const float* __restrict__ ln1s, const float* __restrict__ ln1b,
    const float* __restrict__ gW2, const float* __restrict__ gb2,
    const float* __restrict__ ln2s, const float* __restrict__ ln2b,
    float* __restrict__ h2out)
{
  __shared__ float xs[1024];
  __shared__ float h1s[512];
  __shared__ float red[8];
  int b = blockIdx.x, t = threadIdx.x;
  const float* xr = x + b * 1024;
  #pragma unroll
  for (int i = 0; i < 4; ++i) xs[t + i * 256] = xr[t + i * 256];
  __syncthreads();

  // layer1: thread computes outputs o=2t, 2t+1 (512 outputs)
  float a0 = 0.f, a1 = 0.f;
  for (int d = 0; d < 1024; ++d) {
    float xv = xs[d];
    float2 w = *(const float2*)&gW1[d * 512 + 2 * t];
    a0 = fmaf(xv, w.x, a0);
    a1 = fmaf(xv, w.y, a1);
  }
  a0 += gb1[2 * t]; a1 += gb1[2 * t + 1];
  float s = a0 + a1, sq = a0 * a0 + a1 * a1;
  block_sum2(s, sq, red, t);
  float mu = s * (1.f / 512.f);
  float var = sq * (1.f / 512.f) - mu * mu;
  float inv = rsqrtf(var + EPS_);
  h1s[2 * t]     = fmaxf((a0 - mu) * inv * ln1s[2 * t]     + ln1b[2 * t],     0.f);
  h1s[2 * t + 1] = fmaxf((a1 - mu) * inv * ln1s[2 * t + 1] + ln1b[2 * t + 1], 0.f);
  __syncthreads();

  // layer2: thread computes output o=t (256 outputs)
  float acc = 0.f;
  for (int h = 0; h < 512; ++h) acc = fmaf(h1s[h], gW2[h * 256 + t], acc);
  acc += gb2[t];
  float s2 = acc, sq2 = acc * acc;
  block_sum2(s2, sq2, red, t);
  float mu2 = s2 * (1.f / 256.f);
  float var2 = sq2 * (1.f / 256.f) - mu2 * mu2;
  float inv2 = rsqrtf(var2 + EPS_);
  h2out[b * 256 + t] = fmaxf((acc - mu2) * inv2 * ln2s[t] + ln2b[t], 0.f);
}

// ---------------- K2: logits = h2 @ gW3 + gb3  (128 x 102400, K=256) ----------------
// Register-tiled fp32 GEMM: block = 64 cols x all 128 rows; thread = 8 rows x 4 cols.
// Round-2 fix: round-1's rolling 8-deep prefetch collapsed to ~2 in flight
// (VGPR_Count=64 -- allocator moved loads next to uses). Force depth 16 with
// two NAMED 8-wide batches whose live ranges span a full 8-iter compute block:
// compute(pA) overlaps pB's loads and vice versa. Issue-to-use distance =
// 16 kk-iters (~1024cy FMA) > ~900cy HBM latency. kk order unchanged ->
// bit-identical accumulation.
__global__ __launch_bounds__(256, 4) void gemm3_kernel(
    const float* __restrict__ h2, const float* __restrict__ gW3,
    const float* __restrict__ gb3, float* __restrict__ logits)
{
  __shared__ float h2t[64 * 132];  // [kk][b], stride 132: 16B-aligned rows, conflict-free b128 reads
  int t = threadIdx.x;
  int col0 = blockIdx.x * 64;
  int c4 = (t & 15) * 4;
  int r8 = (t >> 4) * 8;
  float acc[8][4];
  #pragma unroll
  for (int i = 0; i < 8; ++i)
    #pragma unroll
    for (int j = 0; j < 4; ++j) acc[i][j] = 0.f;

  int bb = t >> 1;              // staging: row 0..127
  int k0 = (t & 1) * 32;        // staging: k offset 0 or 32

  #pragma unroll 1
  for (int c = 0; c < 4; ++c) {
    // prologue: issue BOTH batches (16 outstanding 16B loads) before staging
    const float* wp = &gW3[(c * 64) * MD + col0 + c4];
    float4 pA[8], pB[8];
    #pragma unroll
    for (int u = 0; u < 8; ++u) pA[u] = *(const float4*)(wp + u * MD);
    #pragma unroll
    for (int u = 0; u < 8; ++u) pB[u] = *(const float4*)(wp + (8 + u) * MD);

    // stage h2[:, c*64 .. c*64+63] transposed into LDS (float4 reads, 2-way-free writes)
    {
      const float* hp = &h2[bb * 256 + c * 64 + k0];
      #pragma unroll
      for (int j = 0; j < 8; ++j) {
        float4 hv = *(const float4*)(hp + j * 4);
        int k = k0 + j * 4;
        h2t[(k + 0) * 132 + bb] = hv.x;
        h2t[(k + 1) * 132 + bb] = hv.y;
        h2t[(k + 2) * 132 + bb] = hv.z;
        h2t[(k + 3) * 132 + bb] = hv.w;
      }
    }
    __syncthreads();

    // main loop: 8 groups of 8 kk, processed as 4 pairs (pA group, pB group).
    // While computing one batch, the other batch's refill loads are in flight.
    const float* wl = wp + 16 * MD;   // next rows to fetch: kk = 16
    #pragma unroll 1
    for (int kgp = 0; kgp < 3; ++kgp) {
      int kb = kgp * 16;
      // compute kk = kb..kb+7 from pA; refill pA <- kk = kb+16..kb+23
      #pragma unroll
      for (int u = 0; u < 8; ++u) {
        float4 bf = pA[u];
        pA[u] = *(const float4*)(wl + u * MD);
        float4 af0 = *(const float4*)&h2t[(kb + u) * 132 + r8];
        float4 af1 = *(const float4*)&h2t[(kb + u) * 132 + r8 + 4];
        float a[8] = {af0.x, af0.y, af0.z, af0.w, af1.x, af1.y, af1.z, af1.w};
        float bv[4] = {bf.x, bf.y, bf.z, bf.w};
        #pragma unroll
        for (int i = 0; i < 8; ++i)
          #pragma unroll
          for (int j = 0; j < 4; ++j) acc[i][j] = fmaf(a[i], bv[j], acc[i][j]);
      }
      wl += 8 * MD;
      // compute kk = kb+8..kb+15 from pB; refill pB <- kk = kb+24..kb+31
      #pragma unroll
      for (int u = 0; u < 8; ++u) {
        float4 bf = pB[u];
        pB[u] = *(const float4*)(wl + u * MD);
        float4 af0 = *(const float4*)&h2t[(kb + 8 + u) * 132 + r8];
        float4 af1 = *(const float4*)&h2t[(kb + 8 + u) * 132 + r8 + 4];
        float a[8] = {af0.x, af0.y, af0.z, af0.w, af1.x, af1.y, af1.z, af1.w};
        float bv[4] = {bf.x, bf.y, bf.z, bf.w};
        #pragma unroll
        for (int i = 0; i < 8; ++i)
          #pragma unroll
          for (int j = 0; j < 4; ++j) acc[i][j] = fmaf(a[i], bv[j], acc[i][j]);
      }
      wl += 8 * MD;
    }
    // epilogue: kk = 48..55 from pA, kk = 56..63 from pB (no refills)
    #pragma unroll
    for (int u = 0; u < 8; ++u) {
      float4 bf = pA[u];
      float4 af0 = *(const float4*)&h2t[(48 + u) * 132 + r8];
      float4 af1 = *(const float4*)&h2t[(48 + u) * 132 + r8 + 4];
      float a[8] = {af0.x, af0.y, af0.z, af0.w, af1.x, af1.y, af1.z, af1.w};
      float bv[4] = {bf.x, bf.y, bf.z, bf.w};
      #pragma unroll
      for (int i = 0; i < 8; ++i)
        #pragma unroll
        for (int j = 0; j < 4; ++j) acc[i][j] = fmaf(a[i], bv[j], acc[i][j]);
    }
    #pragma unroll
    for (int u = 0; u < 8; ++u) {
      float4 bf = pB[u];
      float4 af0 = *(const float4*)&h2t[(56 + u) * 132 + r8];
      float4 af1 = *(const float4*)&h2t[(56 + u) * 132 + r8 + 4];
      float a[8] = {af0.x, af0.y, af0.z, af0.w, af1.x, af1.y, af1.z, af1.w};
      float bv[4] = {bf.x, bf.y, bf.z, bf.w};
      #pragma unroll
      for (int i = 0; i < 8; ++i)
        #pragma unroll
        for (int j = 0; j < 4; ++j) acc[i][j] = fmaf(a[i], bv[j], acc[i][j]);
    }
    __syncthreads();
  }

  float4 bias = *(const float4*)&gb3[col0 + c4];
  #pragma unroll
  for (int i = 0; i < 8; ++i) {
    float4 o;
    o.x = acc[i][0] + bias.x; o.y = acc[i][1] + bias.y;
    o.z = acc[i][2] + bias.z; o.w = acc[i][3] + bias.w;
    *(float4*)&logits[(r8 + i) * MD + col0 + c4] = o;
  }
}

// ---------------- K3: softmax + top-5 + gathers + synergy + t1 (per (b,m) row) ----------------
__global__ __launch_bounds__(256) void tail_kernel(
    const float* __restrict__ x, const float* __restrict__ gumbel,
    const float* __restrict__ sW1, const float* __restrict__ sb1,
    const float* __restrict__ yW1, const float* __restrict__ yb1,
    const float* __restrict__ yW2, const float* __restrict__ yb2,
    const float* __restrict__ logits, float* __restrict__ probs,
    float* __restrict__ syn, float* __restrict__ t1ws)
{
  __shared__ float red[8];
  __shared__ float redv[4];
  __shared__ int   redi[4];
  __shared__ int   winner;
  int row = blockIdx.x;       // row = b*100 + m
  int t = threadIdx.x;
  int b = row / 100;
  const float* lg = logits + row * 1024;
  const float* gm = gumbel + row * 1024;

  // z = (logit + gumbel) / tau, tau = 0.5
  float z[4];
  #pragma unroll
  for (int i = 0; i < 4; ++i) z[i] = (lg[t + i * 256] + gm[t + i * 256]) * 2.0f;
  float mx = fmaxf(fmaxf(z[0], z[1]), fmaxf(z[2], z[3]));
  mx = block_max(mx, red, t);
  float p[4]; float ls = 0.f;
  #pragma unroll
  for (int i = 0; i < 4; ++i) { p[i] = expf(z[i] - mx); ls += p[i]; }
  float denom = block_sum(ls, red, t);
  float inv = 1.f / denom;
  float v[4];
  #pragma unroll
  for (int i = 0; i < 4; ++i) {
    v[i] = p[i] * inv;
    probs[row * 1024 + t + i * 256] = v[i];
  }

  // top-5 on written prob values; tie-break: lower index first (jax.lax.top_k stable order)
  float t1acc = sb1[t];
  float u1acc = yb1[t];
  for (int jsel = 0; jsel < 5; ++jsel) {
    float bv = v[0]; int bi = t;          // idx = i*256 + t
    #pragma unroll
    for (int i = 1; i < 4; ++i) {
      int idx = i * 256 + t;
      if (v[i] > bv || (v[i] == bv && idx < bi)) { bv = v[i]; bi = idx; }
    }
    #pragma unroll
    for (int off = 1; off < 64; off <<= 1) {
      float ov = __shfl_xor(bv, off);
      int oi = __shfl_xor(bi, off);
      if (ov > bv || (ov == bv && oi < bi)) { bv = ov; bi = oi; }
    }
    if ((t & 63) == 0) { redv[t >> 6] = bv; redi[t >> 6] = bi; }
    __syncthreads();
    if (t == 0) {
      float wv = redv[0]; int wi = redi[0];
      #pragma unroll
      for (int w = 1; w < 4; ++w)
        if (redv[w] > wv || (redv[w] == wv && redi[w] < wi)) { wv = redv[w]; wi = redi[w]; }
      winner = wi;
    }
    __syncthreads();
    int w = winner;
    if ((w & 255) == t) v[w >> 8] = -1.f;   // mask selected
    float xv = x[b * 1024 + w];             // uniform (scalar) load
    t1acc = fmaf(xv, sW1[(jsel * 1024 + w) * 256 + t], t1acc);
    u1acc = fmaf(xv, yW1[(jsel * 1024 + w) * 256 + t], u1acc);
    __syncthreads();
  }

  float t1v = fmaxf(t1acc, 0.f);
  float u1v = fmaxf(u1acc, 0.f);
  t1ws[row * 256 + t] = t1v;

  // synergy = tanh(u1 . yW2 + yb2)
  float part = u1v * yW2[t];
  float dsum = block_sum(part, red, t);
  if (t == 0) syn[row] = tanhf(dsum + yb2[0]);
}

// ---------------- K4: scores = sigmoid(relu(t1 @ sW2 + sb2) @ sW3 + sb3) ----------------
// Block = 64 rows x 128 cols, K=256; thread = 8 rows x 4 cols.
__global__ __launch_bounds__(256) void scorer2_kernel(
    const float* __restrict__ t1, const float* __restrict__ sW2,
    const float* __restrict__ sb2, const float* __restrict__ sW3,
    const float* __restrict__ sb3, float* __restrict__ scores)
{
  __shared__ float t1t[64 * 68];   // [kk][row], stride 68 (16B-aligned)
  __shared__ float red[64 * 32];
  int t = threadIdx.x;
  int row0 = blockIdx.x * 64;
  int c4 = (t & 31) * 4;
  int r8 = (t >> 5) * 8;
  float acc[8][4];
  #pragma unroll
  for (int i = 0; i < 8; ++i)
    #pragma unroll
    for (int j = 0; j < 4; ++j) acc[i][j] = 0.f;

  for (int c = 0; c < 4; ++c) {
    #pragma unroll
    for (int p = 0; p < 16; ++p) {
      int rr = p * 4 + (t >> 6);
      int kk = t & 63;
      t1t[kk * 68 + rr] = t1[(row0 + rr) * 256 + c * 64 + kk];
    }
    __syncthreads();
    #pragma unroll 4
    for (int kk = 0; kk < 64; ++kk) {
      float4 bf = *(const float4*)&sW2[(c * 64 + kk) * 128 + c4];
      float4 a0 = *(const float4*)&t1t[kk * 68 + r8];
      float4 a1 = *(const float4*)&t1t[kk * 68 + r8 + 4];
      float a[8] = {a0.x, a0.y, a0.z, a0.w, a1.x, a1.y, a1.z, a1.w};
      float bv[4] = {bf.x, bf.y, bf.z, bf.w};
      #pragma unroll
      for (int i = 0; i < 8; ++i)
        #pragma unroll
        for (int j = 0; j < 4; ++j) acc[i][j] = fmaf(a[i], bv[j], acc[i][j]);
    }
    __syncthreads();
  }

  float4 b2 = *(const float4*)&sb2[c4];
  float4 w3 = *(const float4*)&sW3[c4];
  #pragma unroll
  for (int i = 0; i < 8; ++i) {
    float s = fmaxf(acc[i][0] + b2.x, 0.f) * w3.x
            + fmaxf(acc[i][1] + b2.y, 0.f) * w3.y
            + fmaxf(acc[i][2] + b2.z, 0.f) * w3.z
            + fmaxf(acc[i][3] + b2.w, 0.f) * w3.w;
    red[(r8 + i) * 32 + (t & 31)] = s;
  }
  __syncthreads();
  if (t < 64) {
    float s = sb3[0];
    #pragma unroll
    for (int g = 0; g < 32; ++g) s += red[t * 32 + g];
    scores[row0 + t] = 1.f / (1.f + expf(-s));
  }
}

extern "C" void kernel_launch(void* const* d_in, const int* in_sizes, int n_in,
                              void* d_out, int out_size, void* d_ws, size_t ws_size,
                              hipStream_t stream) {
  const float* x    = (const float*)d_in[0];
  const float* gum  = (const float*)d_in[1];
  const float* gW1  = (const float*)d_in[2];
  const float* gb1  = (const float*)d_in[3];
  const float* ln1s = (const float*)d_in[4];
  const float* ln1b = (const float*)d_in[5];
  const float* gW2  = (const float*)d_in[6];
  const float* gb2  = (const float*)d_in[7];
  const float* ln2s = (const float*)d_in[8];
  const float* ln2b = (const float*)d_in[9];
  const float* gW3  = (const float*)d_in[10];
  const float* gb3  = (const float*)d_in[11];
  const float* sW1  = (const float*)d_in[12];
  const float* sb1  = (const float*)d_in[13];
  const float* sW2  = (const float*)d_in[14];
  const float* sb2  = (const float*)d_in[15];
  const float* sW3  = (const float*)d_in[16];
  const float* sb3  = (const float*)d_in[17];
  const float* yW1  = (const float*)d_in[18];
  const float* yb1  = (const float*)d_in[19];
  const float* yW2  = (const float*)d_in[20];
  const float* yb2  = (const float*)d_in[21];

  float* out    = (float*)d_out;
  float* probs  = out;
  float* scores = out + OFF_SCORES;
  float* syn    = out + OFF_SYN;
  float* logits = out + OFF_LOGITS;

  float* h2 = (float*)d_ws;                              // 128*256 f32 (131072 floats)
  float* t1 = (float*)((char*)d_ws + 131072 * 4);        // 12800*256 f32 = 13.1 MB

  gen_mlp_kernel<<<128, 256, 0, stream>>>(x, gW1, gb1, ln1s, ln1b, gW2, gb2, ln2s, ln2b, h2);
  gemm3_kernel<<<1600, 256, 0, stream>>>(h2, gW3, gb3, logits);
  tail_kernel<<<12800, 256, 0, stream>>>(x, gum, sW1, sb1, yW1, yb1, yW2, yb2,
                                         logits, probs, syn, t1);
  scorer2_kernel<<<200, 256, 0, stream>>>(t1, sW2, sb2, sW3, sb3, scores);
}

// Round 3
// 543.244 us; speedup vs baseline: 1.0357x; 1.0357x over previous
//
#include <hip/hip_runtime.h>
#include <math.h>

// Shapes
#define B_   128
#define D_   1024
#define H_   256
#define M_   100
#define K_   5
#define MD   102400   // M_*D_
#define EPS_ 1e-5f

// d_out layout (f32): probs[128*100*1024], scores[12800], syn[12800], logits[128*100*1024]
#define OFF_SCORES 13107200
#define OFF_SYN    13120000
#define OFF_LOGITS 13132800

// ---------------- reduction helpers ----------------
__device__ __forceinline__ float block_sum(float v, float* red, int t) {
  #pragma unroll
  for (int off = 1; off < 64; off <<= 1) v += __shfl_xor(v, off);
  if ((t & 63) == 0) red[t >> 6] = v;
  __syncthreads();
  float s = red[0] + red[1] + red[2] + red[3];
  __syncthreads();
  return s;
}

__device__ __forceinline__ float block_max(float v, float* red, int t) {
  #pragma unroll
  for (int off = 1; off < 64; off <<= 1) v = fmaxf(v, __shfl_xor(v, off));
  if ((t & 63) == 0) red[t >> 6] = v;
  __syncthreads();
  float s = fmaxf(fmaxf(red[0], red[1]), fmaxf(red[2], red[3]));
  __syncthreads();
  return s;
}

__device__ __forceinline__ void block_sum2(float& a, float& b, float* red, int t) {
  #pragma unroll
  for (int off = 1; off < 64; off <<= 1) { a += __shfl_xor(a, off); b += __shfl_xor(b, off); }
  if ((t & 63) == 0) { red[(t >> 6) * 2] = a; red[(t >> 6) * 2 + 1] = b; }
  __syncthreads();
  a = red[0] + red[2] + red[4] + red[6];
  b = red[1] + red[3] + red[5] + red[7];
  __syncthreads();
}

// ---------------- K1: generator layers 1+2 (per batch row) ----------------
__global__ __launch_bounds__(256) void gen_mlp_kernel(
    const float* __restrict__ x,
    const float* __restrict__ gW1, const float* __restrict__ gb1,
    const float* __restrict__ ln1s, const float* __restrict__ ln1b,
    const float* __restrict__ gW2, const float* __restrict__ gb2,
    const float* __restrict__ ln2s, const float* __restrict__ ln2b,
    float* __restrict__ h2out)
{
  __shared__ float xs[1024];
  __shared__ float h1s[512];
  __shared__ float red[8];
  int b = blockIdx.x, t = threadIdx.x;
  const float* xr = x + b * 1024;
  #pragma unroll
  for (int i = 0; i < 4; ++i) xs[t + i * 256] = xr[t + i * 256];
  __syncthreads();

  // layer1: thread computes outputs o=2t, 2t+1 (512 outputs)
  float a0 = 0.f, a1 = 0.f;
  for (int d = 0; d < 1024; ++d) {
    float xv = xs[d];
    float2 w = *(const float2*)&gW1[d * 512 + 2 * t];
    a0 = fmaf(xv, w.x, a0);
    a1 = fmaf(xv, w.y, a1);
  }
  a0 += gb1[2 * t]; a1 += gb1[2 * t + 1];
  float s = a0 + a1, sq = a0 * a0 + a1 * a1;
  block_sum2(s, sq, red, t);
  float mu = s * (1.f / 512.f);
  float var = sq * (1.f / 512.f) - mu * mu;
  float inv = rsqrtf(var + EPS_);
  h1s[2 * t]     = fmaxf((a0 - mu) * inv * ln1s[2 * t]     + ln1b[2 * t],     0.f);
  h1s[2 * t + 1] = fmaxf((a1 - mu) * inv * ln1s[2 * t + 1] + ln1b[2 * t + 1], 0.f);
  __syncthreads();

  // layer2: thread computes output o=t (256 outputs)
  float acc = 0.f;
  for (int h = 0; h < 512; ++h) acc = fmaf(h1s[h], gW2[h * 256 + t], acc);
  acc += gb2[t];
  float s2 = acc, sq2 = acc * acc;
  block_sum2(s2, sq2, red, t);
  float mu2 = s2 * (1.f / 256.f);
  float var2 = sq2 * (1.f / 256.f) - mu2 * mu2;
  float inv2 = rsqrtf(var2 + EPS_);
  h2out[b * 256 + t] = fmaxf((acc - mu2) * inv2 * ln2s[t] + ln2b[t], 0.f);
}

// ---------------- K2: logits = h2 @ gW3 + gb3  (128 x 102400, K=256) ----------------
// Round-3 restructure: scalar-pipe W streaming.
//   lane = output row, thread = 1 row x 32 cols. W address depends only on
//   blockIdx + loop counters + readfirstlane-derived wave id -> wave-uniform
//   -> s_load_dwordx16 into SGPRs (no VGPR pressure, lgkmcnt-pipelined by the
//   compiler). h2 comes from a tiny transposed LDS tile; one ds_read_b32
//   feeds 32 FMAs. LDS 16.6 KB + ~50 VGPRs -> 8 blocks/CU (full occupancy).
//   kk accumulation order unchanged (0..255 sequential) -> bit-identical.
__global__ __launch_bounds__(256, 8) void gemm3_kernel(
    const float* __restrict__ h2, const float* __restrict__ gW3,
    const float* __restrict__ gb3, float* __restrict__ logits)
{
  __shared__ float h2s[32 * 130];   // [kk][row], stride 130: 2-way (free) banking
  int t = threadIdx.x;
  int lane = t & 63;
  int t0 = __builtin_amdgcn_readfirstlane(t);
  int rg = (t0 >> 6) & 1;           // row group: rows rg*64 + lane
  int cg = t0 >> 7;                 // col group: 32 cols
  int row = rg * 64 + lane;
  int col0 = blockIdx.x * 64 + cg * 32;

  float acc[32];
  #pragma unroll
  for (int c = 0; c < 32; ++c) acc[c] = 0.f;

  int bb = t >> 1;                  // staging: h2 row 0..127
  int ks = (t & 1) * 16;            // staging: kk offset 0 or 16

  #pragma unroll 1
  for (int kt = 0; kt < 8; ++kt) {
    // prefetch this tile's h2 slice (issued before barrier; overlaps prev tail)
    const float* hp = &h2[bb * 256 + kt * 32 + ks];
    float4 a0 = *(const float4*)(hp + 0);
    float4 a1 = *(const float4*)(hp + 4);
    float4 a2 = *(const float4*)(hp + 8);
    float4 a3 = *(const float4*)(hp + 12);
    __syncthreads();                // previous tile fully consumed
    h2s[(ks +  0) * 130 + bb] = a0.x;
    h2s[(ks +  1) * 130 + bb] = a0.y;
    h2s[(ks +  2) * 130 + bb] = a0.z;
    h2s[(ks +  3) * 130 + bb] = a0.w;
    h2s[(ks +  4) * 130 + bb] = a1.x;
    h2s[(ks +  5) * 130 + bb] = a1.y;
    h2s[(ks +  6) * 130 + bb] = a1.z;
    h2s[(ks +  7) * 130 + bb] = a1.w;
    h2s[(ks +  8) * 130 + bb] = a2.x;
    h2s[(ks +  9) * 130 + bb] = a2.y;
    h2s[(ks + 10) * 130 + bb] = a2.z;
    h2s[(ks + 11) * 130 + bb] = a2.w;
    h2s[(ks + 12) * 130 + bb] = a3.x;
    h2s[(ks + 13) * 130 + bb] = a3.y;
    h2s[(ks + 14) * 130 + bb] = a3.z;
    h2s[(ks + 15) * 130 + bb] = a3.w;
    __syncthreads();

    const float* wb = &gW3[(kt * 32) * MD + col0];   // wave-uniform
    #pragma unroll 2
    for (int kk = 0; kk < 32; ++kk) {
      float hv = h2s[kk * 130 + row];                // per-lane ds_read_b32
      const float* wr = wb + kk * MD;                // wave-uniform -> s_load
      #pragma unroll
      for (int c = 0; c < 32; ++c)
        acc[c] = fmaf(hv, wr[c], acc[c]);
    }
  }

  float* op = &logits[row * MD + col0];
  const float* gp = &gb3[col0];                       // wave-uniform -> s_load
  #pragma unroll
  for (int q = 0; q < 8; ++q) {
    float4 o;
    o.x = acc[4 * q + 0] + gp[4 * q + 0];
    o.y = acc[4 * q + 1] + gp[4 * q + 1];
    o.z = acc[4 * q + 2] + gp[4 * q + 2];
    o.w = acc[4 * q + 3] + gp[4 * q + 3];
    *(float4*)(op + 4 * q) = o;
  }
}

// ---------------- K3: softmax + top-5 + gathers + synergy + t1 (per (b,m) row) ----------------
__global__ __launch_bounds__(256) void tail_kernel(
    const float* __restrict__ x, const float* __restrict__ gumbel,
    const float* __restrict__ sW1, const float* __restrict__ sb1,
    const float* __restrict__ yW1, const float* __restrict__ yb1,
    const float* __restrict__ yW2, const float* __restrict__ yb2,
    const float* __restrict__ logits, float* __restrict__ probs,
    float* __restrict__ syn, float* __restrict__ t1ws)
{
  __shared__ float red[8];
  __shared__ float redv[4];
  __shared__ int   redi[4];
  __shared__ int   winner;
  int row = blockIdx.x;       // row = b*100 + m
  int t = threadIdx.x;
  int b = row / 100;
  const float* lg = logits + row * 1024;
  const float* gm = gumbel + row * 1024;

  // z = (logit + gumbel) / tau, tau = 0.5
  float z[4];
  #pragma unroll
  for (int i = 0; i < 4; ++i) z[i] = (lg[t + i * 256] + gm[t + i * 256]) * 2.0f;
  float mx = fmaxf(fmaxf(z[0], z[1]), fmaxf(z[2], z[3]));
  mx = block_max(mx, red, t);
  float p[4]; float ls = 0.f;
  #pragma unroll
  for (int i = 0; i < 4; ++i) { p[i] = expf(z[i] - mx); ls += p[i]; }
  float denom = block_sum(ls, red, t);
  float inv = 1.f / denom;
  float v[4];
  #pragma unroll
  for (int i = 0; i < 4; ++i) {
    v[i] = p[i] * inv;
    probs[row * 1024 + t + i * 256] = v[i];
  }

  // top-5 on written prob values; tie-break: lower index first (jax.lax.top_k stable order)
  float t1acc = sb1[t];
  float u1acc = yb1[t];
  for (int jsel = 0; jsel < 5; ++jsel) {
    float bv = v[0]; int bi = t;          // idx = i*256 + t
    #pragma unroll
    for (int i = 1; i < 4; ++i) {
      int idx = i * 256 + t;
      if (v[i] > bv || (v[i] == bv && idx < bi)) { bv = v[i]; bi = idx; }
    }
    #pragma unroll
    for (int off = 1; off < 64; off <<= 1) {
      float ov = __shfl_xor(bv, off);
      int oi = __shfl_xor(bi, off);
      if (ov > bv || (ov == bv && oi < bi)) { bv = ov; bi = oi; }
    }
    if ((t & 63) == 0) { redv[t >> 6] = bv; redi[t >> 6] = bi; }
    __syncthreads();
    if (t == 0) {
      float wv = redv[0]; int wi = redi[0];
      #pragma unroll
      for (int w = 1; w < 4; ++w)
        if (redv[w] > wv || (redv[w] == wv && redi[w] < wi)) { wv = redv[w]; wi = redi[w]; }
      winner = wi;
    }
    __syncthreads();
    int w = winner;
    if ((w & 255) == t) v[w >> 8] = -1.f;   // mask selected
    float xv = x[b * 1024 + w];             // uniform (scalar) load
    t1acc = fmaf(xv, sW1[(jsel * 1024 + w) * 256 + t], t1acc);
    u1acc = fmaf(xv, yW1[(jsel * 1024 + w) * 256 + t], u1acc);
    __syncthreads();
  }

  float t1v = fmaxf(t1acc, 0.f);
  float u1v = fmaxf(u1acc, 0.f);
  t1ws[row * 256 + t] = t1v;

  // synergy = tanh(u1 . yW2 + yb2)
  float part = u1v * yW2[t];
  float dsum = block_sum(part, red, t);
  if (t == 0) syn[row] = tanhf(dsum + yb2[0]);
}

// ---------------- K4: scores = sigmoid(relu(t1 @ sW2 + sb2) @ sW3 + sb3) ----------------
// Block = 64 rows x 128 cols, K=256; thread = 8 rows x 4 cols.
__global__ __launch_bounds__(256) void scorer2_kernel(
    const float* __restrict__ t1, const float* __restrict__ sW2,
    const float* __restrict__ sb2, const float* __restrict__ sW3,
    const float* __restrict__ sb3, float* __restrict__ scores)
{
  __shared__ float t1t[64 * 68];   // [kk][row], stride 68 (16B-aligned)
  __shared__ float red[64 * 32];
  int t = threadIdx.x;
  int row0 = blockIdx.x * 64;
  int c4 = (t & 31) * 4;
  int r8 = (t >> 5) * 8;
  float acc[8][4];
  #pragma unroll
  for (int i = 0; i < 8; ++i)
    #pragma unroll
    for (int j = 0; j < 4; ++j) acc[i][j] = 0.f;

  for (int c = 0; c < 4; ++c) {
    #pragma unroll
    for (int p = 0; p < 16; ++p) {
      int rr = p * 4 + (t >> 6);
      int kk = t & 63;
      t1t[kk * 68 + rr] = t1[(row0 + rr) * 256 + c * 64 + kk];
    }
    __syncthreads();
    #pragma unroll 4
    for (int kk = 0; kk < 64; ++kk) {
      float4 bf = *(const float4*)&sW2[(c * 64 + kk) * 128 + c4];
      float4 a0 = *(const float4*)&t1t[kk * 68 + r8];
      float4 a1 = *(const float4*)&t1t[kk * 68 + r8 + 4];
      float a[8] = {a0.x, a0.y, a0.z, a0.w, a1.x, a1.y, a1.z, a1.w};
      float bv[4] = {bf.x, bf.y, bf.z, bf.w};
      #pragma unroll
      for (int i = 0; i < 8; ++i)
        #pragma unroll
        for (int j = 0; j < 4; ++j) acc[i][j] = fmaf(a[i], bv[j], acc[i][j]);
    }
    __syncthreads();
  }

  float4 b2 = *(const float4*)&sb2[c4];
  float4 w3 = *(const float4*)&sW3[c4];
  #pragma unroll
  for (int i = 0; i < 8; ++i) {
    float s = fmaxf(acc[i][0] + b2.x, 0.f) * w3.x
            + fmaxf(acc[i][1] + b2.y, 0.f) * w3.y
            + fmaxf(acc[i][2] + b2.z, 0.f) * w3.z
            + fmaxf(acc[i][3] + b2.w, 0.f) * w3.w;
    red[(r8 + i) * 32 + (t & 31)] = s;
  }
  __syncthreads();
  if (t < 64) {
    float s = sb3[0];
    #pragma unroll
    for (int g = 0; g < 32; ++g) s += red[t * 32 + g];
    scores[row0 + t] = 1.f / (1.f + expf(-s));
  }
}

extern "C" void kernel_launch(void* const* d_in, const int* in_sizes, int n_in,
                              void* d_out, int out_size, void* d_ws, size_t ws_size,
                              hipStream_t stream) {
  const float* x    = (const float*)d_in[0];
  const float* gum  = (const float*)d_in[1];
  const float* gW1  = (const float*)d_in[2];
  const float* gb1  = (const float*)d_in[3];
  const float* ln1s = (const float*)d_in[4];
  const float* ln1b = (const float*)d_in[5];
  const float* gW2  = (const float*)d_in[6];
  const float* gb2  = (const float*)d_in[7];
  const float* ln2s = (const float*)d_in[8];
  const float* ln2b = (const float*)d_in[9];
  const float* gW3  = (const float*)d_in[10];
  const float* gb3  = (const float*)d_in[11];
  const float* sW1  = (const float*)d_in[12];
  const float* sb1  = (const float*)d_in[13];
  const float* sW2  = (const float*)d_in[14];
  const float* sb2  = (const float*)d_in[15];
  const float* sW3  = (const float*)d_in[16];
  const float* sb3  = (const float*)d_in[17];
  const float* yW1  = (const float*)d_in[18];
  const float* yb1  = (const float*)d_in[19];
  const float* yW2  = (const float*)d_in[20];
  const float* yb2  = (const float*)d_in[21];

  float* out    = (float*)d_out;
  float* probs  = out;
  float* scores = out + OFF_SCORES;
  float* syn    = out + OFF_SYN;
  float* logits = out + OFF_LOGITS;

  float* h2 = (float*)d_ws;                              // 128*256 f32 (131072 floats)
  float* t1 = (float*)((char*)d_ws + 131072 * 4);        // 12800*256 f32 = 13.1 MB

  gen_mlp_kernel<<<128, 256, 0, stream>>>(x, gW1, gb1, ln1s, ln1b, gW2, gb2, ln2s, ln2b, h2);
  gemm3_kernel<<<1600, 256, 0, stream>>>(h2, gW3, gb3, logits);
  tail_kernel<<<12800, 256, 0, stream>>>(x, gum, sW1, sb1, yW1, yb1, yW2, yb2,
                                         logits, probs, syn, t1);
  scorer2_kernel<<<200, 256, 0, stream>>>(t1, sW2, sb2, sW3, sb3, scores);
}

// Round 4
// 466.306 us; speedup vs baseline: 1.2066x; 1.1650x over previous
//
#include <hip/hip_runtime.h>
#include <math.h>

// Shapes
#define B_   128
#define D_   1024
#define H_   256
#define M_   100
#define K_   5
#define MD   102400   // M_*D_
#define EPS_ 1e-5f

// d_out layout (f32): probs[128*100*1024], scores[12800], syn[12800], logits[128*100*1024]
#define OFF_SCORES 13107200
#define OFF_SYN    13120000
#define OFF_LOGITS 13132800

// ---------------- reduction helpers ----------------
__device__ __forceinline__ float block_sum(float v, float* red, int t) {
  #pragma unroll
  for (int off = 1; off < 64; off <<= 1) v += __shfl_xor(v, off);
  if ((t & 63) == 0) red[t >> 6] = v;
  __syncthreads();
  float s = red[0] + red[1] + red[2] + red[3];
  __syncthreads();
  return s;
}

__device__ __forceinline__ float block_max(float v, float* red, int t) {
  #pragma unroll
  for (int off = 1; off < 64; off <<= 1) v = fmaxf(v, __shfl_xor(v, off));
  if ((t & 63) == 0) red[t >> 6] = v;
  __syncthreads();
  float s = fmaxf(fmaxf(red[0], red[1]), fmaxf(red[2], red[3]));
  __syncthreads();
  return s;
}

__device__ __forceinline__ void block_sum2(float& a, float& b, float* red, int t) {
  #pragma unroll
  for (int off = 1; off < 64; off <<= 1) { a += __shfl_xor(a, off); b += __shfl_xor(b, off); }
  if ((t & 63) == 0) { red[(t >> 6) * 2] = a; red[(t >> 6) * 2 + 1] = b; }
  __syncthreads();
  a = red[0] + red[2] + red[4] + red[6];
  b = red[1] + red[3] + red[5] + red[7];
  __syncthreads();
}

// ---------------- K1: generator layers 1+2 (per batch row) ----------------
__global__ __launch_bounds__(256) void gen_mlp_kernel(
    const float* __restrict__ x,
    const float* __restrict__ gW1, const float* __restrict__ gb1,
    const float* __restrict__ ln1s, const float* __restrict__ ln1b,
    const float* __restrict__ gW2, const float* __restrict__ gb2,
    const float* __restrict__ ln2s, const float* __restrict__ ln2b,
    float* __restrict__ h2out)
{
  __shared__ float xs[1024];
  __shared__ float h1s[512];
  __shared__ float red[8];
  int b = blockIdx.x, t = threadIdx.x;
  const float* xr = x + b * 1024;
  #pragma unroll
  for (int i = 0; i < 4; ++i) xs[t + i * 256] = xr[t + i * 256];
  __syncthreads();

  // layer1: thread computes outputs o=2t, 2t+1 (512 outputs)
  float a0 = 0.f, a1 = 0.f;
  for (int d = 0; d < 1024; ++d) {
    float xv = xs[d];
    float2 w = *(const float2*)&gW1[d * 512 + 2 * t];
    a0 = fmaf(xv, w.x, a0);
    a1 = fmaf(xv, w.y, a1);
  }
  a0 += gb1[2 * t]; a1 += gb1[2 * t + 1];
  float s = a0 + a1, sq = a0 * a0 + a1 * a1;
  block_sum2(s, sq, red, t);
  float mu = s * (1.f / 512.f);
  float var = sq * (1.f / 512.f) - mu * mu;
  float inv = rsqrtf(var + EPS_);
  h1s[2 * t]     = fmaxf((a0 - mu) * inv * ln1s[2 * t]     + ln1b[2 * t],     0.f);
  h1s[2 * t + 1] = fmaxf((a1 - mu) * inv * ln1s[2 * t + 1] + ln1b[2 * t + 1], 0.f);
  __syncthreads();

  // layer2: thread computes output o=t (256 outputs)
  float acc = 0.f;
  for (int h = 0; h < 512; ++h) acc = fmaf(h1s[h], gW2[h * 256 + t], acc);
  acc += gb2[t];
  float s2 = acc, sq2 = acc * acc;
  block_sum2(s2, sq2, red, t);
  float mu2 = s2 * (1.f / 256.f);
  float var2 = sq2 * (1.f / 256.f) - mu2 * mu2;
  float inv2 = rsqrtf(var2 + EPS_);
  h2out[b * 256 + t] = fmaxf((acc - mu2) * inv2 * ln2s[t] + ln2b[t], 0.f);
}

// ---------------- K2: logits = h2 @ gW3 + gb3  (128 x 102400, K=256) ----------------
// Round-4: DMA-pipelined GEMM. W streamed via global_load_lds (vmcnt-tracked,
// zero VGPR/SGPR cost) into a double-buffered LDS tile; 2-phase raw-barrier
// schedule with per-wave counted waits (NOT __syncthreads -- that drains
// vmcnt(0) and serializes the DMA). Next tile's W-DMA + h2 loads issue before
// the compute phase, flying under ~2000cy of FMA (> ~900cy HBM latency).
// Block tile 128 rows x 128 cols, BK=32, thread = 8r x 8c (split col frags at
// cg*4 and 64+cg*4 -> all LDS reads 2-way/broadcast = conflict-free).
// kk accumulation order 0..255 sequential -> bit-identical logits.
__global__ __launch_bounds__(256, 3) void gemm3_kernel(
    const float* __restrict__ h2, const float* __restrict__ gW3,
    const float* __restrict__ gb3, float* __restrict__ logits)
{
  __shared__ float h2t[32 * 132];       // A tile: [kk][row], stride 132
  __shared__ float Wlds[2 * 32 * 128];  // B tiles: dbuf [kk][col], lane-linear for DMA
  int t = threadIdx.x;
  int lane = t & 63;
  int w = t >> 6;                       // wave id 0..3
  int rg8 = (t >> 4) * 8;               // row-group base 0..120
  int cg4 = (t & 15) * 4;               // col-frag base 0..60
  long col0 = (long)blockIdx.x * 128;

  int bb = t >> 1;                      // h2 staging: row 0..127
  int ks = (t & 1) * 16;                // h2 staging: kk offset 0 or 16

  int krl = lane >> 5;                  // DMA: sub-row 0/1
  int cid = (lane & 31) * 4;            // DMA: col float offset

  float acc[8][8];
  #pragma unroll
  for (int i = 0; i < 8; ++i)
    #pragma unroll
    for (int j = 0; j < 8; ++j) acc[i][j] = 0.f;

  // ---- prologue: issue W(0) DMA + h2(0) register loads ----
  #pragma unroll
  for (int p = 0; p < 4; ++p) {
    int kkrow = p * 8 + w * 2;          // wave-uniform
    const float* g = gW3 + (long)(kkrow + krl) * MD + col0 + cid;
    float* l = &Wlds[kkrow * 128];
    __builtin_amdgcn_global_load_lds(
        (const __attribute__((address_space(1))) void*)g,
        (__attribute__((address_space(3))) void*)l, 16, 0, 0);
  }
  const float* hp = &h2[bb * 256 + ks];
  float4 ha = *(const float4*)(hp + 0);
  float4 hb = *(const float4*)(hp + 4);
  float4 hc = *(const float4*)(hp + 8);
  float4 hd = *(const float4*)(hp + 12);

  #pragma unroll 1
  for (int kt = 0; kt < 8; ++kt) {
    // wait: this tile's W DMA landed in LDS, h2 regs arrived
    asm volatile("s_waitcnt vmcnt(0)" ::: "memory");
    __builtin_amdgcn_s_barrier();       // all waves' DMA done, prev compute done

    // write h2 tile (transposed) into LDS
    {
      float vals[16] = {ha.x, ha.y, ha.z, ha.w, hb.x, hb.y, hb.z, hb.w,
                        hc.x, hc.y, hc.z, hc.w, hd.x, hd.y, hd.z, hd.w};
      #pragma unroll
      for (int j = 0; j < 16; ++j) h2t[(ks + j) * 132 + bb] = vals[j];
    }

    // issue NEXT tile's W DMA + h2 loads (they fly under the compute below)
    if (kt + 1 < 8) {
      #pragma unroll
      for (int p = 0; p < 4; ++p) {
        int kkrow = p * 8 + w * 2;
        const float* g = gW3 + ((long)(kt + 1) * 32 + kkrow + krl) * MD + col0 + cid;
        float* l = &Wlds[((kt + 1) & 1) * 4096 + kkrow * 128];
        __builtin_amdgcn_global_load_lds(
            (const __attribute__((address_space(1))) void*)g,
            (__attribute__((address_space(3))) void*)l, 16, 0, 0);
      }
      const float* hq = &h2[bb * 256 + (kt + 1) * 32 + ks];
      ha = *(const float4*)(hq + 0);
      hb = *(const float4*)(hq + 4);
      hc = *(const float4*)(hq + 8);
      hd = *(const float4*)(hq + 12);
    }

    asm volatile("s_waitcnt lgkmcnt(0)" ::: "memory");  // my h2t writes done
    __builtin_amdgcn_s_barrier();                        // all waves' h2t visible

    // compute this tile
    const float* Wb = &Wlds[(kt & 1) * 4096];
    #pragma unroll 8
    for (int kk = 0; kk < 32; ++kk) {
      float4 a0 = *(const float4*)&h2t[kk * 132 + rg8];
      float4 a1 = *(const float4*)&h2t[kk * 132 + rg8 + 4];
      float4 b0 = *(const float4*)&Wb[kk * 128 + cg4];
      float4 b1 = *(const float4*)&Wb[kk * 128 + 64 + cg4];
      float a[8] = {a0.x, a0.y, a0.z, a0.w, a1.x, a1.y, a1.z, a1.w};
      float bv[8] = {b0.x, b0.y, b0.z, b0.w, b1.x, b1.y, b1.z, b1.w};
      #pragma unroll
      for (int i = 0; i < 8; ++i)
        #pragma unroll
        for (int j = 0; j < 8; ++j)
          acc[i][j] = fmaf(a[i], bv[j], acc[i][j]);
    }
  }

  // epilogue: bias + store (cols cg4..cg4+3 and 64+cg4..64+cg4+3)
  float4 bias0 = *(const float4*)&gb3[col0 + cg4];
  float4 bias1 = *(const float4*)&gb3[col0 + 64 + cg4];
  #pragma unroll
  for (int i = 0; i < 8; ++i) {
    long row = rg8 + i;
    float4 o0, o1;
    o0.x = acc[i][0] + bias0.x; o0.y = acc[i][1] + bias0.y;
    o0.z = acc[i][2] + bias0.z; o0.w = acc[i][3] + bias0.w;
    o1.x = acc[i][4] + bias1.x; o1.y = acc[i][5] + bias1.y;
    o1.z = acc[i][6] + bias1.z; o1.w = acc[i][7] + bias1.w;
    *(float4*)&logits[row * MD + col0 + cg4] = o0;
    *(float4*)&logits[row * MD + col0 + 64 + cg4] = o1;
  }
}

// ---------------- K3: softmax + top-5 + gathers + synergy + t1 (per (b,m) row) ----------------
__global__ __launch_bounds__(256) void tail_kernel(
    const float* __restrict__ x, const float* __restrict__ gumbel,
    const float* __restrict__ sW1, const float* __restrict__ sb1,
    const float* __restrict__ yW1, const float* __restrict__ yb1,
    const float* __restrict__ yW2, const float* __restrict__ yb2,
    const float* __restrict__ logits, float* __restrict__ probs,
    float* __restrict__ syn, float* __restrict__ t1ws)
{
  __shared__ float red[8];
  __shared__ float redv[4];
  __shared__ int   redi[4];
  __shared__ int   winner;
  int row = blockIdx.x;       // row = b*100 + m
  int t = threadIdx.x;
  int b = row / 100;
  const float* lg = logits + row * 1024;
  const float* gm = gumbel + row * 1024;

  // z = (logit + gumbel) / tau, tau = 0.5
  float z[4];
  #pragma unroll
  for (int i = 0; i < 4; ++i) z[i] = (lg[t + i * 256] + gm[t + i * 256]) * 2.0f;
  float mx = fmaxf(fmaxf(z[0], z[1]), fmaxf(z[2], z[3]));
  mx = block_max(mx, red, t);
  float p[4]; float ls = 0.f;
  #pragma unroll
  for (int i = 0; i < 4; ++i) { p[i] = expf(z[i] - mx); ls += p[i]; }
  float denom = block_sum(ls, red, t);
  float inv = 1.f / denom;
  float v[4];
  #pragma unroll
  for (int i = 0; i < 4; ++i) {
    v[i] = p[i] * inv;
    probs[row * 1024 + t + i * 256] = v[i];
  }

  // top-5 on written prob values; tie-break: lower index first (jax.lax.top_k stable order)
  float t1acc = sb1[t];
  float u1acc = yb1[t];
  for (int jsel = 0; jsel < 5; ++jsel) {
    float bv = v[0]; int bi = t;          // idx = i*256 + t
    #pragma unroll
    for (int i = 1; i < 4; ++i) {
      int idx = i * 256 + t;
      if (v[i] > bv || (v[i] == bv && idx < bi)) { bv = v[i]; bi = idx; }
    }
    #pragma unroll
    for (int off = 1; off < 64; off <<= 1) {
      float ov = __shfl_xor(bv, off);
      int oi = __shfl_xor(bi, off);
      if (ov > bv || (ov == bv && oi < bi)) { bv = ov; bi = oi; }
    }
    if ((t & 63) == 0) { redv[t >> 6] = bv; redi[t >> 6] = bi; }
    __syncthreads();
    if (t == 0) {
      float wv = redv[0]; int wi = redi[0];
      #pragma unroll
      for (int w = 1; w < 4; ++w)
        if (redv[w] > wv || (redv[w] == wv && redi[w] < wi)) { wv = redv[w]; wi = redi[w]; }
      winner = wi;
    }
    __syncthreads();
    int w = winner;
    if ((w & 255) == t) v[w >> 8] = -1.f;   // mask selected
    float xv = x[b * 1024 + w];             // uniform (scalar) load
    t1acc = fmaf(xv, sW1[(jsel * 1024 + w) * 256 + t], t1acc);
    u1acc = fmaf(xv, yW1[(jsel * 1024 + w) * 256 + t], u1acc);
    __syncthreads();
  }

  float t1v = fmaxf(t1acc, 0.f);
  float u1v = fmaxf(u1acc, 0.f);
  t1ws[row * 256 + t] = t1v;

  // synergy = tanh(u1 . yW2 + yb2)
  float part = u1v * yW2[t];
  float dsum = block_sum(part, red, t);
  if (t == 0) syn[row] = tanhf(dsum + yb2[0]);
}

// ---------------- K4: scores = sigmoid(relu(t1 @ sW2 + sb2) @ sW3 + sb3) ----------------
// Block = 64 rows x 128 cols, K=256; thread = 8 rows x 4 cols.
__global__ __launch_bounds__(256) void scorer2_kernel(
    const float* __restrict__ t1, const float* __restrict__ sW2,
    const float* __restrict__ sb2, const float* __restrict__ sW3,
    const float* __restrict__ sb3, float* __restrict__ scores)
{
  __shared__ float t1t[64 * 68];   // [kk][row], stride 68 (16B-aligned)
  __shared__ float red[64 * 32];
  int t = threadIdx.x;
  int row0 = blockIdx.x * 64;
  int c4 = (t & 31) * 4;
  int r8 = (t >> 5) * 8;
  float acc[8][4];
  #pragma unroll
  for (int i = 0; i < 8; ++i)
    #pragma unroll
    for (int j = 0; j < 4; ++j) acc[i][j] = 0.f;

  for (int c = 0; c < 4; ++c) {
    #pragma unroll
    for (int p = 0; p < 16; ++p) {
      int rr = p * 4 + (t >> 6);
      int kk = t & 63;
      t1t[kk * 68 + rr] = t1[(row0 + rr) * 256 + c * 64 + kk];
    }
    __syncthreads();
    #pragma unroll 4
    for (int kk = 0; kk < 64; ++kk) {
      float4 bf = *(const float4*)&sW2[(c * 64 + kk) * 128 + c4];
      float4 a0 = *(const float4*)&t1t[kk * 68 + r8];
      float4 a1 = *(const float4*)&t1t[kk * 68 + r8 + 4];
      float a[8] = {a0.x, a0.y, a0.z, a0.w, a1.x, a1.y, a1.z, a1.w};
      float bv[4] = {bf.x, bf.y, bf.z, bf.w};
      #pragma unroll
      for (int i = 0; i < 8; ++i)
        #pragma unroll
        for (int j = 0; j < 4; ++j) acc[i][j] = fmaf(a[i], bv[j], acc[i][j]);
    }
    __syncthreads();
  }

  float4 b2 = *(const float4*)&sb2[c4];
  float4 w3 = *(const float4*)&sW3[c4];
  #pragma unroll
  for (int i = 0; i < 8; ++i) {
    float s = fmaxf(acc[i][0] + b2.x, 0.f) * w3.x
            + fmaxf(acc[i][1] + b2.y, 0.f) * w3.y
            + fmaxf(acc[i][2] + b2.z, 0.f) * w3.z
            + fmaxf(acc[i][3] + b2.w, 0.f) * w3.w;
    red[(r8 + i) * 32 + (t & 31)] = s;
  }
  __syncthreads();
  if (t < 64) {
    float s = sb3[0];
    #pragma unroll
    for (int g = 0; g < 32; ++g) s += red[t * 32 + g];
    scores[row0 + t] = 1.f / (1.f + expf(-s));
  }
}

extern "C" void kernel_launch(void* const* d_in, const int* in_sizes, int n_in,
                              void* d_out, int out_size, void* d_ws, size_t ws_size,
                              hipStream_t stream) {
  const float* x    = (const float*)d_in[0];
  const float* gum  = (const float*)d_in[1];
  const float* gW1  = (const float*)d_in[2];
  const float* gb1  = (const float*)d_in[3];
  const float* ln1s = (const float*)d_in[4];
  const float* ln1b = (const float*)d_in[5];
  const float* gW2  = (const float*)d_in[6];
  const float* gb2  = (const float*)d_in[7];
  const float* ln2s = (const float*)d_in[8];
  const float* ln2b = (const float*)d_in[9];
  const float* gW3  = (const float*)d_in[10];
  const float* gb3  = (const float*)d_in[11];
  const float* sW1  = (const float*)d_in[12];
  const float* sb1  = (const float*)d_in[13];
  const float* sW2  = (const float*)d_in[14];
  const float* sb2  = (const float*)d_in[15];
  const float* sW3  = (const float*)d_in[16];
  const float* sb3  = (const float*)d_in[17];
  const float* yW1  = (const float*)d_in[18];
  const float* yb1  = (const float*)d_in[19];
  const float* yW2  = (const float*)d_in[20];
  const float* yb2  = (const float*)d_in[21];

  float* out    = (float*)d_out;
  float* probs  = out;
  float* scores = out + OFF_SCORES;
  float* syn    = out + OFF_SYN;
  float* logits = out + OFF_LOGITS;

  float* h2 = (float*)d_ws;                              // 128*256 f32 (131072 floats)
  float* t1 = (float*)((char*)d_ws + 131072 * 4);        // 12800*256 f32 = 13.1 MB

  gen_mlp_kernel<<<128, 256, 0, stream>>>(x, gW1, gb1, ln1s, ln1b, gW2, gb2, ln2s, ln2b, h2);
  gemm3_kernel<<<800, 256, 0, stream>>>(h2, gW3, gb3, logits);
  tail_kernel<<<12800, 256, 0, stream>>>(x, gum, sW1, sb1, yW1, yb1, yW2, yb2,
                                         logits, probs, syn, t1);
  scorer2_kernel<<<200, 256, 0, stream>>>(t1, sW2, sb2, sW3, sb3, scores);
}